// Round 2
// baseline (1055.982 us; speedup 1.0000x reference)
//
#include <hip/hip_runtime.h>
#include <hip/hip_bf16.h>

// x [B=2, C=16, T=31, H=256, W=256] fp32
#define TDIM 31
#define TS   65536                 // t stride (H*W)
#define CS   (TDIM * TS)           // c stride = 2,031,616
#define BS   (16 * CS)             // b stride
#define NTOT (2 * BS)
#define K1_BLOCKS 2048             // 64 positions per block
#define GAP_INV (1.0f / (31.0f * 65536.0f))

__device__ __forceinline__ float frcp(float v) { return __builtin_amdgcn_rcpf(v); }
__device__ __forceinline__ float fexp2(float v) { return __builtin_amdgcn_exp2f(v); }
__device__ __forceinline__ float ftanh(float x) {
    float e = fexp2(x * 2.8853900817779268f);   // exp(2x)
    return 1.0f - 2.0f * frcp(e + 1.0f);
}
__device__ __forceinline__ float fsigm(float x) {
    float e = fexp2(x * -1.4426950408889634f);  // exp(-x)
    return frcp(1.0f + e);
}

// Block = 64 positions (p0..p0+63) x all 16 channels.
// Wave q (q = tid>>6) computes output channels 4q..4q+3 for all 64 positions.
// Weights: wave-uniform rows -> SGPRs via scalar loads. Intermediate 'a'
// exchanged through double-buffered LDS (stride 65 -> 2-way banks = free).
__global__ __launch_bounds__(256, 6) void k1_gates_scan(
    const float* __restrict__ x,
    const float* __restrict__ wf1, const float* __restrict__ bf1,
    const float* __restrict__ wf2, const float* __restrict__ bf2,
    const float* __restrict__ ww1, const float* __restrict__ bw1,
    const float* __restrict__ ww2, const float* __restrict__ bw2,
    float* __restrict__ out, float* __restrict__ partials) {

    __shared__ float sAf[2][16][65];
    __shared__ float sAw[2][16][65];

    const int tid  = threadIdx.x;
    const int lane = tid & 63;
    const int q    = __builtin_amdgcn_readfirstlane(tid >> 6);  // wave's channel quad
    const int blk  = blockIdx.x;
    const int b    = blk >> 10;                 // 1024 blocks per batch
    const int p    = ((blk & 1023) << 6) + lane;

    const float* __restrict__ xp = x   + (size_t)b * BS + p;
    float* __restrict__       op = out + (size_t)b * BS + p;

    // wave-uniform row blocks (row-major [o][c], rows 4q..4q+3 contiguous)
    const float* __restrict__ Wf1q = wf1 + q * 64;
    const float* __restrict__ Ww1q = ww1 + q * 64;
    const float* __restrict__ Wf2q = wf2 + q * 64;
    const float* __restrict__ Ww2q = ww2 + q * 64;
    const float bf1q[4] = {bf1[q*4+0], bf1[q*4+1], bf1[q*4+2], bf1[q*4+3]};
    const float bw1q[4] = {bw1[q*4+0], bw1[q*4+1], bw1[q*4+2], bw1[q*4+3]};
    const float bf2q[4] = {bf2[q*4+0], bf2[q*4+1], bf2[q*4+2], bf2[q*4+3]};
    const float bw2q[4] = {bw2[q*4+0], bw2[q*4+1], bw2[q*4+2], bw2[q*4+3]};

    float h[4] = {0.f,0.f,0.f,0.f}, s[4] = {0.f,0.f,0.f,0.f};

#pragma unroll 1
    for (int t = 0; t < TDIM; ++t) {
        const int buf = t & 1;
        const float* __restrict__ xt = xp + (size_t)t * TS;

        float xv[16];
#pragma unroll
        for (int c = 0; c < 16; ++c) xv[c] = xt[(size_t)c * CS];

        // conv1, f-branch, own 4 outputs
        float af[4] = {bf1q[0], bf1q[1], bf1q[2], bf1q[3]};
#pragma unroll
        for (int c = 0; c < 16; ++c) {
#pragma unroll
            for (int k = 0; k < 4; ++k) af[k] = fmaf(Wf1q[k*16+c], xv[c], af[k]);
        }
        // conv1, w-branch
        float aw[4] = {bw1q[0], bw1q[1], bw1q[2], bw1q[3]};
#pragma unroll
        for (int c = 0; c < 16; ++c) {
#pragma unroll
            for (int k = 0; k < 4; ++k) aw[k] = fmaf(Ww1q[k*16+c], xv[c], aw[k]);
        }
#pragma unroll
        for (int k = 0; k < 4; ++k) {
            sAf[buf][q*4+k][lane] = ftanh(af[k]);
            sAw[buf][q*4+k][lane] = ftanh(aw[k]);
        }
        __syncthreads();

        // conv2 for both branches, reading full 16-vector a from LDS
        float zf[4] = {bf2q[0], bf2q[1], bf2q[2], bf2q[3]};
        float fw[4] = {bw2q[0], bw2q[1], bw2q[2], bw2q[3]};
#pragma unroll
        for (int c = 0; c < 16; ++c) {
            const float a1 = sAf[buf][c][lane];
#pragma unroll
            for (int k = 0; k < 4; ++k) zf[k] = fmaf(Wf2q[k*16+c], a1, zf[k]);
            const float a2 = sAw[buf][c][lane];
#pragma unroll
            for (int k = 0; k < 4; ++k) fw[k] = fmaf(Ww2q[k*16+c], a2, fw[k]);
        }
#pragma unroll
        for (int k = 0; k < 4; ++k) {
            const float z = ftanh(zf[k]);
            const float f = fsigm(fw[k]);
            h[k] = fmaf(f, h[k] - z, z);     // f*h + (1-f)*z
            s[k] += h[k];
            op[(size_t)(q*4+k) * CS + (size_t)t * TS] = h[k];
        }
    }

    // reduce s over the wave's 64 positions (deterministic)
#pragma unroll
    for (int k = 0; k < 4; ++k) {
        float v = s[k];
#pragma unroll
        for (int off = 32; off > 0; off >>= 1) v += __shfl_down(v, off, 64);
        s[k] = v;
    }
    if (lane == 0) {
#pragma unroll
        for (int k = 0; k < 4; ++k) partials[blk * 16 + q * 4 + k] = s[k];
    }
}

__global__ void k2_attention(const float* __restrict__ partials,
                             const float* __restrict__ wsca,
                             const float* __restrict__ bsca,
                             float* __restrict__ att) {
    __shared__ float red[2][16][16];
    __shared__ float gap[2][16];
    const int tid = threadIdx.x;            // 512 threads
    {
        const int b = tid >> 8, c = (tid >> 4) & 15, seg = tid & 15;
        float sum = 0.0f;
        const int base = b * 1024 + seg * 64;
        for (int j = 0; j < 64; ++j) sum += partials[(base + j) * 16 + c];
        red[b][c][seg] = sum;
    }
    __syncthreads();
    if (tid < 32) {
        const int b = tid >> 4, c = tid & 15;
        float sum = 0.0f;
        for (int s2 = 0; s2 < 16; ++s2) sum += red[b][c][s2];
        gap[b][c] = sum * GAP_INV;
    }
    __syncthreads();
    if (tid < 32) {
        const int b = tid >> 4, o = tid & 15;
        float acc = bsca[o];
#pragma unroll
        for (int c = 0; c < 16; ++c) acc = fmaf(wsca[o*16+c], gap[b][c], acc);
        att[b*16+o] = fsigm(acc);
    }
}

__global__ __launch_bounds__(256) void k3_scale(float* __restrict__ out,
                                                const float* __restrict__ att) {
    __shared__ float sA[32];
    if (threadIdx.x < 32) sA[threadIdx.x] = att[threadIdx.x];
    __syncthreads();
    const int NV4 = NTOT / 4;
    const int CSV = CS / 4;                 // 507,904 -> i4/CSV == b*16+c exactly
    float4* __restrict__ o4 = (float4*)out;
    for (int i = blockIdx.x * 256 + threadIdx.x; i < NV4; i += gridDim.x * 256) {
        const int bc = i / CSV;
        const float a = sA[bc];
        float4 v = o4[i];
        v.x *= a; v.y *= a; v.z *= a; v.w *= a;
        o4[i] = v;
    }
}

extern "C" void kernel_launch(void* const* d_in, const int* in_sizes, int n_in,
                              void* d_out, int out_size, void* d_ws, size_t ws_size,
                              hipStream_t stream) {
    const float* x    = (const float*)d_in[0];
    const float* wf1  = (const float*)d_in[1];
    const float* bf1  = (const float*)d_in[2];
    const float* wf2  = (const float*)d_in[3];
    const float* bf2  = (const float*)d_in[4];
    const float* ww1  = (const float*)d_in[5];
    const float* bw1  = (const float*)d_in[6];
    const float* ww2  = (const float*)d_in[7];
    const float* bw2  = (const float*)d_in[8];
    const float* wsca = (const float*)d_in[9];
    const float* bsca = (const float*)d_in[10];
    float* out = (float*)d_out;

    float* partials = (float*)d_ws;                 // K1_BLOCKS*16 floats = 128 KB
    float* att      = partials + K1_BLOCKS * 16;    // 32 floats

    k1_gates_scan<<<K1_BLOCKS, 256, 0, stream>>>(x, wf1, bf1, wf2, bf2,
                                                 ww1, bw1, ww2, bw2, out, partials);
    k2_attention<<<1, 512, 0, stream>>>(partials, wsca, bsca, att);
    k3_scale<<<2048, 256, 0, stream>>>(out, att);
}

// Round 3
// 415.302 us; speedup vs baseline: 2.5427x; 2.5427x over previous
//
#include <hip/hip_runtime.h>
#include <hip/hip_bf16.h>

// x [B=2, C=16, T=31, H=256, W=256] fp32
#define TDIM 31
#define TS   65536                 // t stride (H*W)
#define CS   (TDIM * TS)           // c stride = 2,031,616
#define BS   (16 * CS)             // b stride
#define NTOT (2 * BS)
#define POS_PER_BLK 16
#define BLKS_PER_B  4096           // 65536 / 16
#define K1_BLOCKS   8192
#define LPAD 18                    // padded channel stride in gate LDS arrays
#define GAP_INV (1.0f / (31.0f * 65536.0f))

__device__ __forceinline__ float frcp(float v) { return __builtin_amdgcn_rcpf(v); }
__device__ __forceinline__ float fexp2_(float v) { return __builtin_amdgcn_exp2f(v); }
__device__ __forceinline__ float ftanh(float x) {
    float e = fexp2_(x * 2.8853900817779268f);   // exp(2x)
    return 1.0f - 2.0f * frcp(e + 1.0f);
}
__device__ __forceinline__ float fsigm(float x) {
    float e = fexp2_(x * -1.4426950408889634f);  // exp(-x)
    return frcp(1.0f + e);
}

// Block: 16 positions x all 31 timesteps.
// Phase 1 (t-parallel): thread tid<496 owns one (t,p); computes both FFNs for
//   all 16 channels in registers; weights via LDS b128 broadcast reads.
// Phase 2 (t-serial): thread tid<256 owns one (c,p); runs the 31-step
//   recurrence out of LDS, stores h coalesced, accumulates GAP partials.
__global__ __launch_bounds__(512, 4) void k1_fused(
    const float* __restrict__ x,
    const float* __restrict__ wf1, const float* __restrict__ bf1,
    const float* __restrict__ wf2, const float* __restrict__ bf2,
    const float* __restrict__ ww1, const float* __restrict__ bw1,
    const float* __restrict__ ww2, const float* __restrict__ bw2,
    float* __restrict__ out, float* __restrict__ partials)
{
    __shared__ float zA[TDIM][POS_PER_BLK][LPAD];   // 35.7 KB
    __shared__ float fA[TDIM][POS_PER_BLK][LPAD];   // 35.7 KB
    __shared__ float sW[4][256];                    // wf1, wf2, ww1, ww2 (row-major [o][c])
    __shared__ float sB[4][16];

    const int tid = threadIdx.x;
    if (tid < 256) {
        sW[0][tid] = wf1[tid]; sW[1][tid] = wf2[tid];
        sW[2][tid] = ww1[tid]; sW[3][tid] = ww2[tid];
    } else if (tid < 272) {
        const int i = tid - 256;
        sB[0][i] = bf1[i]; sB[1][i] = bf2[i]; sB[2][i] = bw1[i]; sB[3][i] = bw2[i];
    }
    __syncthreads();

    const int blk = blockIdx.x;
    const int b   = blk >> 12;                         // 4096 blocks per batch
    const int p0  = (blk & (BLKS_PER_B - 1)) * POS_PER_BLK;

    if (tid < 496) {
        const int t = tid >> 4, p = tid & 15;
        const float* __restrict__ xp = x + (size_t)b * BS + (size_t)t * TS + p0 + p;

        float xv[16];
#pragma unroll
        for (int c = 0; c < 16; ++c) xv[c] = xp[(size_t)c * CS];

        // conv1 (both branches), outputs tanh'd into af/aw
        float af[16], aw[16];
#pragma unroll
        for (int o = 0; o < 16; ++o) {
            float a1 = sB[0][o], a2 = sB[2][o];
#pragma unroll
            for (int cq = 0; cq < 4; ++cq) {
                const float4 w1 = *(const float4*)&sW[0][o * 16 + cq * 4];
                const float4 w2 = *(const float4*)&sW[2][o * 16 + cq * 4];
                a1 = fmaf(w1.x, xv[cq*4+0], a1); a1 = fmaf(w1.y, xv[cq*4+1], a1);
                a1 = fmaf(w1.z, xv[cq*4+2], a1); a1 = fmaf(w1.w, xv[cq*4+3], a1);
                a2 = fmaf(w2.x, xv[cq*4+0], a2); a2 = fmaf(w2.y, xv[cq*4+1], a2);
                a2 = fmaf(w2.z, xv[cq*4+2], a2); a2 = fmaf(w2.w, xv[cq*4+3], a2);
            }
            af[o] = ftanh(a1);
            aw[o] = ftanh(a2);
        }
        // conv2 (both branches), write z/f straight to LDS per output channel
#pragma unroll
        for (int o = 0; o < 16; ++o) {
            float a1 = sB[1][o], a2 = sB[3][o];
#pragma unroll
            for (int cq = 0; cq < 4; ++cq) {
                const float4 w1 = *(const float4*)&sW[1][o * 16 + cq * 4];
                const float4 w2 = *(const float4*)&sW[3][o * 16 + cq * 4];
                a1 = fmaf(w1.x, af[cq*4+0], a1); a1 = fmaf(w1.y, af[cq*4+1], a1);
                a1 = fmaf(w1.z, af[cq*4+2], a1); a1 = fmaf(w1.w, af[cq*4+3], a1);
                a2 = fmaf(w2.x, aw[cq*4+0], a2); a2 = fmaf(w2.y, aw[cq*4+1], a2);
                a2 = fmaf(w2.z, aw[cq*4+2], a2); a2 = fmaf(w2.w, aw[cq*4+3], a2);
            }
            zA[t][p][o] = ftanh(a1);
            fA[t][p][o] = fsigm(a2);
        }
    }
    __syncthreads();

    if (tid < 256) {
        const int c = tid >> 4, p = tid & 15;       // wave = 4 c-groups x 16 p -> 64B store segments
        float* __restrict__ op = out + (size_t)b * BS + (size_t)c * CS + p0 + p;
        float h = 0.0f, s = 0.0f;
        for (int t = 0; t < TDIM; ++t) {
            const float z = zA[t][p][c];
            const float f = fA[t][p][c];
            h = fmaf(f, h - z, z);                  // f*h + (1-f)*z
            s += h;
            op[(size_t)t * TS] = h;
        }
#pragma unroll
        for (int off = 8; off; off >>= 1) s += __shfl_down(s, off, 16);
        if (p == 0) partials[blk * 16 + c] = s;
    }
}

__global__ void k2_attention(const float* __restrict__ partials,
                             const float* __restrict__ wsca,
                             const float* __restrict__ bsca,
                             float* __restrict__ att) {
    __shared__ float red[2][16][16];
    __shared__ float gap[2][16];
    const int tid = threadIdx.x;                    // 512 threads
    {
        const int b = tid >> 8, c = (tid >> 4) & 15, seg = tid & 15;
        const int base = b * BLKS_PER_B + seg * (BLKS_PER_B / 16);
        float sum = 0.0f;
        for (int i = 0; i < BLKS_PER_B / 16; ++i) sum += partials[(base + i) * 16 + c];
        red[b][c][seg] = sum;
    }
    __syncthreads();
    if (tid < 32) {
        const int b = tid >> 4, c = tid & 15;
        float sum = 0.0f;
#pragma unroll
        for (int k = 0; k < 16; ++k) sum += red[b][c][k];
        gap[b][c] = sum * GAP_INV;
    }
    __syncthreads();
    if (tid < 32) {
        const int b = tid >> 4, o = tid & 15;
        float acc = bsca[o];
#pragma unroll
        for (int c = 0; c < 16; ++c) acc = fmaf(wsca[o * 16 + c], gap[b][c], acc);
        att[b * 16 + o] = fsigm(acc);
    }
}

__global__ __launch_bounds__(256) void k3_scale(float* __restrict__ out,
                                                const float* __restrict__ att) {
    __shared__ float sA[32];
    if (threadIdx.x < 32) sA[threadIdx.x] = att[threadIdx.x];
    __syncthreads();
    const int NV4 = NTOT / 4;
    const int CSV = CS / 4;                 // 507,904 -> i4/CSV == b*16+c exactly
    float4* __restrict__ o4 = (float4*)out;
    for (int i = blockIdx.x * 256 + threadIdx.x; i < NV4; i += gridDim.x * 256) {
        const int bc = i / CSV;
        const float a = sA[bc];
        float4 v = o4[i];
        v.x *= a; v.y *= a; v.z *= a; v.w *= a;
        o4[i] = v;
    }
}

extern "C" void kernel_launch(void* const* d_in, const int* in_sizes, int n_in,
                              void* d_out, int out_size, void* d_ws, size_t ws_size,
                              hipStream_t stream) {
    const float* x    = (const float*)d_in[0];
    const float* wf1  = (const float*)d_in[1];
    const float* bf1  = (const float*)d_in[2];
    const float* wf2  = (const float*)d_in[3];
    const float* bf2  = (const float*)d_in[4];
    const float* ww1  = (const float*)d_in[5];
    const float* bw1  = (const float*)d_in[6];
    const float* ww2  = (const float*)d_in[7];
    const float* bw2  = (const float*)d_in[8];
    const float* wsca = (const float*)d_in[9];
    const float* bsca = (const float*)d_in[10];
    float* out = (float*)d_out;

    float* partials = (float*)d_ws;                  // K1_BLOCKS*16 floats = 512 KB
    float* att      = partials + K1_BLOCKS * 16;     // 32 floats

    k1_fused<<<K1_BLOCKS, 512, 0, stream>>>(x, wf1, bf1, wf2, bf2,
                                            ww1, bw1, ww2, bw2, out, partials);
    k2_attention<<<1, 512, 0, stream>>>(partials, wsca, bsca, att);
    k3_scale<<<2048, 256, 0, stream>>>(out, att);
}

// Round 4
// 374.631 us; speedup vs baseline: 2.8187x; 1.1086x over previous
//
#include <hip/hip_runtime.h>
#include <hip/hip_bf16.h>

// x [B=2, C=16, T=31, H=256, W=256] fp32
#define TDIM 31
#define TS   65536                 // t stride (H*W)
#define CS   (TDIM * TS)           // c stride = 2,031,616
#define BS   (16 * CS)             // b stride
#define NTOT (2 * BS)              // 65,011,712
#define K1_BLOCKS 8192             // 16 positions per block
#define GAP_INV (1.0f / (31.0f * 65536.0f))

typedef __attribute__((ext_vector_type(8))) short short8v;     // 8 bf16 (4 VGPR)
typedef __attribute__((ext_vector_type(4))) float f32x4;       // MFMA C/D
typedef __attribute__((ext_vector_type(8))) unsigned short ushort8v;

__device__ __forceinline__ float frcp(float v){ return __builtin_amdgcn_rcpf(v); }
__device__ __forceinline__ float fexp2_(float v){ return __builtin_amdgcn_exp2f(v); }
__device__ __forceinline__ float ftanh(float x){ float e = fexp2_(x*2.8853900817779268f); return 1.0f - 2.0f*frcp(e+1.0f); }
__device__ __forceinline__ float fsigm(float x){ float e = fexp2_(x*-1.4426950408889634f); return frcp(1.0f+e); }
__device__ __forceinline__ unsigned rhu16(float x){ return (__float_as_uint(x) + 0x8000u) >> 16; }
__device__ __forceinline__ float bf2f(unsigned b){ return __uint_as_float(b << 16); }

// Block: 16 positions x all 31 timesteps, 256 threads = 4 waves.
// Phase 1: wave w handles units u = w, w+4, ... (one unit = one timestep of the
//   16 positions). Per unit: B-frag = [Xhi;Xlo] (K=32 split -> fp32-accurate),
//   conv1 = 2 branches x 2 split MFMAs, tanh, afaw through per-wave LDS row,
//   conv2 = 2 MFMAs ([Wf2|0], [0|Ww2] on B2=[af;aw]), z->bf16 LDS, f->f32 LDS.
// Phase 2: thread (c,p) scans 31 steps from LDS, stores h (bf16 to ws or f32
//   to out), accumulates GAP partials.
template<bool BF16H>
__global__ __launch_bounds__(256, 3) void k1_fused(
    const float* __restrict__ x,
    const float* __restrict__ wf1, const float* __restrict__ bf1,
    const float* __restrict__ wf2, const float* __restrict__ bf2,
    const float* __restrict__ ww1, const float* __restrict__ bw1,
    const float* __restrict__ ww2, const float* __restrict__ bw2,
    float* __restrict__ out, unsigned short* __restrict__ hb,
    float* __restrict__ partials)
{
    __shared__ float          sF[TDIM][16][16];          // f gate, f32 (31744 B)
    __shared__ unsigned short sZ[TDIM][16][16];          // z gate, bf16 (15872 B)
    __shared__ alignas(16) char sAfaw[4][1280];          // per-wave a-exchange (5120 B)

    const int tid  = threadIdx.x;
    const int lane = tid & 63;
    const int wv   = tid >> 6;
    const int col  = lane & 15;            // A-row (=o) / B-col (=position)
    const int kg   = lane >> 4;            // k-group: k = kg*8 + i
    const int blk  = blockIdx.x;
    const int b    = blk >> 12;            // 4096 blocks per batch
    const int p0   = (blk & 4095) << 4;

    // ---- weight A-fragments (built once; K=32 logical) ----
    short8v A1f, A2f, A1w, A2w, Af2, Aw2;
    {
        const int c0 = (kg & 1) * 8;       // [W|W] stack: kg0/2 -> cols 0-7, kg1/3 -> 8-15
#pragma unroll
        for (int i = 0; i < 8; ++i) {
            const float w1 = wf1[col*16 + c0 + i];
            unsigned u1 = __float_as_uint(w1);
            float lo1 = w1 - __uint_as_float(u1 & 0xFFFF0000u);
            A1f[i] = (short)(u1 >> 16);
            A2f[i] = (short)(__float_as_uint(lo1) >> 16);
            const float w2 = ww1[col*16 + c0 + i];
            unsigned u2 = __float_as_uint(w2);
            float lo2 = w2 - __uint_as_float(u2 & 0xFFFF0000u);
            A1w[i] = (short)(u2 >> 16);
            A2w[i] = (short)(__float_as_uint(lo2) >> 16);
            const float v2f = wf2[col*16 + c0 + i];
            const float v2w = ww2[col*16 + c0 + i];
            Af2[i] = (kg < 2)  ? (short)rhu16(v2f) : (short)0;   // [Wf2 | 0]
            Aw2[i] = (kg >= 2) ? (short)rhu16(v2w) : (short)0;   // [0 | Ww2]
        }
    }
    float b1f[4], b1w[4], b2f[4], b2w[4];
#pragma unroll
    for (int r = 0; r < 4; ++r) {          // D row o = kg*4 + r
        b1f[r] = bf1[kg*4+r]; b1w[r] = bw1[kg*4+r];
        b2f[r] = bf2[kg*4+r]; b2w[r] = bw2[kg*4+r];
    }

    const f32x4 zf4 = {0.f, 0.f, 0.f, 0.f};

    auto process = [&](int u, const float* xv) {
        // B-frag: k<16 -> Xhi (trunc), k>=16 -> Xlo (residual)
        short8v bx;
#pragma unroll
        for (int i = 0; i < 8; ++i) {
            const unsigned uu = __float_as_uint(xv[i]);
            const float lof = xv[i] - __uint_as_float(uu & 0xFFFF0000u);
            const unsigned lob = __float_as_uint(lof) >> 16;
            const unsigned hib = uu >> 16;
            bx[i] = (short)(kg >= 2 ? lob : hib);
        }
        f32x4 accf = zf4, accw = zf4;
        accf = __builtin_amdgcn_mfma_f32_16x16x32_bf16(A1f, bx, accf, 0, 0, 0);
        accf = __builtin_amdgcn_mfma_f32_16x16x32_bf16(A2f, bx, accf, 0, 0, 0);
        accw = __builtin_amdgcn_mfma_f32_16x16x32_bf16(A1w, bx, accw, 0, 0, 0);
        accw = __builtin_amdgcn_mfma_f32_16x16x32_bf16(A2w, bx, accw, 0, 0, 0);

        // activations -> packed bf16 -> per-wave LDS row (af @0, aw @48)
        const float a0 = ftanh(accf[0]+b1f[0]), a1 = ftanh(accf[1]+b1f[1]);
        const float a2 = ftanh(accf[2]+b1f[2]), a3 = ftanh(accf[3]+b1f[3]);
        const float w0 = ftanh(accw[0]+b1w[0]), w1 = ftanh(accw[1]+b1w[1]);
        const float w2 = ftanh(accw[2]+b1w[2]), w3 = ftanh(accw[3]+b1w[3]);
        char* base = sAfaw[wv] + col * 80;
        *(uint2*)(base + kg*8)      = make_uint2((rhu16(a1)<<16)|rhu16(a0), (rhu16(a3)<<16)|rhu16(a2));
        *(uint2*)(base + 48 + kg*8) = make_uint2((rhu16(w1)<<16)|rhu16(w0), (rhu16(w3)<<16)|rhu16(w2));
        // B2 = [af ; aw]: kg0 af0-7 @0, kg1 af8-15 @16, kg2 aw0-7 @48, kg3 aw8-15 @64
        const short8v b2 = *(const short8v*)(base + ((kg & 1) * 16 + (kg >> 1) * 48));
        f32x4 acz = __builtin_amdgcn_mfma_f32_16x16x32_bf16(Af2, b2, zf4, 0, 0, 0);
        f32x4 acw = __builtin_amdgcn_mfma_f32_16x16x32_bf16(Aw2, b2, zf4, 0, 0, 0);
#pragma unroll
        for (int r = 0; r < 4; ++r) {
            const float z = ftanh(acz[r] + b2f[r]);
            const float f = fsigm(acw[r] + b2w[r]);
            sF[u][kg*4 + r][col] = f;
            sZ[u][kg*4 + r][col] = (unsigned short)rhu16(z);
        }
    };

    // ---- phase 1 with 2-deep load pipeline ----
    const unsigned xbase = (unsigned)b * BS + (unsigned)p0 + (unsigned)col
                         + (unsigned)((kg & 1) * 8) * CS;
    float xa[8], xb_[8];
    {
        const float* xp = x + (size_t)xbase + (size_t)wv * TS;
#pragma unroll
        for (int i = 0; i < 8; ++i) xa[i] = xp[i * CS];
    }
#pragma unroll
    for (int k = 0; k < 8; ++k) {
        const int u  = wv + 4 * k;
        const int un = u + 4;
        if ((k & 1) == 0) {
            if (un < TDIM) {
                const float* xp = x + (size_t)xbase + (size_t)un * TS;
#pragma unroll
                for (int i = 0; i < 8; ++i) xb_[i] = xp[i * CS];
            }
            if (u < TDIM) process(u, xa);
        } else {
            if (un < TDIM) {
                const float* xp = x + (size_t)xbase + (size_t)un * TS;
#pragma unroll
                for (int i = 0; i < 8; ++i) xa[i] = xp[i * CS];
            }
            if (u < TDIM) process(u, xb_);
        }
    }
    __syncthreads();

    // ---- phase 2: scan (thread = (c, p)) ----
    {
        const int c = tid >> 4, p = tid & 15;
        const unsigned oidx = (unsigned)b * BS + (unsigned)c * CS + (unsigned)p0 + (unsigned)p;
        float h = 0.f, s = 0.f;
#pragma unroll 1
        for (int t = 0; t < TDIM; ++t) {
            const float f = sF[t][c][p];
            const float z = bf2f(sZ[t][c][p]);
            h = fmaf(f, h - z, z);          // f*h + (1-f)*z
            s += h;
            if (BF16H) hb[oidx + (unsigned)t * TS] = (unsigned short)rhu16(h);
            else       out[oidx + (unsigned)t * TS] = h;
        }
#pragma unroll
        for (int off = 8; off; off >>= 1) s += __shfl_down(s, off, 16);
        if (p == 0) partials[blk * 16 + c] = s;
    }
}

__global__ __launch_bounds__(1024) void k2_attention(
    const float* __restrict__ partials, const float* __restrict__ wsca,
    const float* __restrict__ bsca, float* __restrict__ att)
{
    __shared__ float red[2][16][32];
    __shared__ float gap[2][16];
    const int tid = threadIdx.x;
    {
        const int b = tid >> 9, c = (tid >> 5) & 15, seg = tid & 31;
        float s = 0.f;
        const float* p = partials + (size_t)(b * 4096 + seg * 128) * 16 + c;
        for (int j = 0; j < 128; ++j) s += p[j * 16];
        red[b][c][seg] = s;
    }
    __syncthreads();
    if (tid < 32) {
        const int b = tid >> 4, c = tid & 15;
        float s = 0.f;
#pragma unroll
        for (int g = 0; g < 32; ++g) s += red[b][c][g];
        gap[b][c] = s * GAP_INV;
    }
    __syncthreads();
    if (tid < 32) {
        const int b = tid >> 4, o = tid & 15;
        float acc = bsca[o];
#pragma unroll
        for (int c = 0; c < 16; ++c) acc = fmaf(wsca[o*16 + c], gap[b][c], acc);
        att[b*16 + o] = fsigm(acc);
    }
}

// bf16-h path: read h (bf16, ws), write fp32 out. grid (248, 32) x 1024: exact.
__global__ __launch_bounds__(1024) void k3_scale_b(
    const unsigned short* __restrict__ hb, const float* __restrict__ att,
    float* __restrict__ out)
{
    const int bc = blockIdx.y;
    const float a = att[bc];
    const unsigned i = blockIdx.x * 1024 + threadIdx.x;     // < 253,952 = CS/8
    const size_t base = (size_t)bc * CS;
    const ushort8v v = ((const ushort8v*)(hb + base))[i];
    float4 o1, o2;
    o1.x = bf2f(v[0])*a; o1.y = bf2f(v[1])*a; o1.z = bf2f(v[2])*a; o1.w = bf2f(v[3])*a;
    o2.x = bf2f(v[4])*a; o2.y = bf2f(v[5])*a; o2.z = bf2f(v[6])*a; o2.w = bf2f(v[7])*a;
    float4* op = (float4*)(out + base);
    op[i*2]     = o1;
    op[i*2 + 1] = o2;
}

// fallback: in-place fp32 scale
__global__ __launch_bounds__(1024) void k3_scale_a(
    const float* __restrict__ att, float* __restrict__ out)
{
    const int bc = blockIdx.y;
    const float a = att[bc];
    const unsigned i = blockIdx.x * 1024 + threadIdx.x;
    float4* op = (float4*)(out + (size_t)bc * CS);
    float4 v1 = op[i*2], v2 = op[i*2 + 1];
    v1.x *= a; v1.y *= a; v1.z *= a; v1.w *= a;
    v2.x *= a; v2.y *= a; v2.z *= a; v2.w *= a;
    op[i*2] = v1; op[i*2 + 1] = v2;
}

extern "C" void kernel_launch(void* const* d_in, const int* in_sizes, int n_in,
                              void* d_out, int out_size, void* d_ws, size_t ws_size,
                              hipStream_t stream) {
    const float* x    = (const float*)d_in[0];
    const float* wf1  = (const float*)d_in[1];
    const float* bf1  = (const float*)d_in[2];
    const float* wf2  = (const float*)d_in[3];
    const float* bf2  = (const float*)d_in[4];
    const float* ww1  = (const float*)d_in[5];
    const float* bw1  = (const float*)d_in[6];
    const float* ww2  = (const float*)d_in[7];
    const float* bw2  = (const float*)d_in[8];
    const float* wsca = (const float*)d_in[9];
    const float* bsca = (const float*)d_in[10];
    float* out = (float*)d_out;

    const size_t hbBytes   = (size_t)NTOT * 2;               // 130,023,424
    const size_t partBytes = (size_t)K1_BLOCKS * 16 * 4;     // 524,288
    const bool bf16h = ws_size >= hbBytes + partBytes + 256;

    unsigned short* hb = (unsigned short*)d_ws;
    float* partials = bf16h ? (float*)((char*)d_ws + hbBytes) : (float*)d_ws;
    float* att = partials + K1_BLOCKS * 16;

    if (bf16h) {
        k1_fused<true><<<K1_BLOCKS, 256, 0, stream>>>(x, wf1, bf1, wf2, bf2,
            ww1, bw1, ww2, bw2, out, hb, partials);
        k2_attention<<<1, 1024, 0, stream>>>(partials, wsca, bsca, att);
        k3_scale_b<<<dim3(248, 32), 1024, 0, stream>>>(hb, att, out);
    } else {
        k1_fused<false><<<K1_BLOCKS, 256, 0, stream>>>(x, wf1, bf1, wf2, bf2,
            ww1, bw1, ww2, bw2, out, hb, partials);
        k2_attention<<<1, 1024, 0, stream>>>(partials, wsca, bsca, att);
        k3_scale_a<<<dim3(248, 32), 1024, 0, stream>>>(att, out);
    }
}

// Round 5
// 357.573 us; speedup vs baseline: 2.9532x; 1.0477x over previous
//
#include <hip/hip_runtime.h>
#include <hip/hip_bf16.h>

// x [B=2, C=16, T=31, H=256, W=256] fp32
#define TDIM 31
#define TS   65536                 // t stride (H*W)
#define CS   (TDIM * TS)           // c stride = 2,031,616
#define BS   (16 * CS)             // b stride
#define NTOT (2 * BS)              // 65,011,712
#define K1_BLOCKS 8192             // 16 positions per block
#define GAP_INV (1.0f / (31.0f * 65536.0f))

typedef __attribute__((ext_vector_type(8))) short short8v;     // 8 bf16 (4 VGPR)
typedef __attribute__((ext_vector_type(4))) float f32x4;       // MFMA C/D
typedef __attribute__((ext_vector_type(8))) unsigned short ushort8v;

__device__ __forceinline__ float frcp(float v){ return __builtin_amdgcn_rcpf(v); }
__device__ __forceinline__ float fexp2_(float v){ return __builtin_amdgcn_exp2f(v); }
__device__ __forceinline__ float ftanh(float x){ float e = fexp2_(x*2.8853900817779268f); return 1.0f - 2.0f*frcp(e+1.0f); }
__device__ __forceinline__ float fsigm(float x){ float e = fexp2_(x*-1.4426950408889634f); return frcp(1.0f+e); }
__device__ __forceinline__ unsigned rhu16(float x){ return (__float_as_uint(x) + 0x8000u) >> 16; }
__device__ __forceinline__ float bf2f(unsigned b){ return __uint_as_float(b << 16); }

// Block: 16 positions x all 31 timesteps, 256 threads = 4 waves.
// Phase 1: wave w handles units u = w, w+4, ... (unit = one t of 16 positions).
//   3-buffer register prefetch (2 units ahead). Per unit: B = [Xhi;Xlo] K-split
//   MFMAs for conv1 (both branches), tanh, LDS a-exchange, conv2 = 2 MFMAs,
//   then (z,f) packed snorm16/unorm16 into one u32 -> one ds_write_b128.
// Phase 2: thread (c,p) scans 31 steps reading one ds_read_b32 per t,
//   stores h (bf16 to ws or f32 to out), accumulates GAP partials.
template<bool BF16H>
__global__ __launch_bounds__(256, 4) void k1_fused(
    const float* __restrict__ x,
    const float* __restrict__ wf1, const float* __restrict__ bf1,
    const float* __restrict__ wf2, const float* __restrict__ bf2,
    const float* __restrict__ ww1, const float* __restrict__ bw1,
    const float* __restrict__ ww2, const float* __restrict__ bw2,
    float* __restrict__ out, unsigned short* __restrict__ hb,
    float* __restrict__ partials)
{
    __shared__ unsigned int sGate[TDIM][16][16];     // (z snorm16)<<16 | f unorm16; 31744 B
    __shared__ alignas(16) char sAfaw[4][1280];      // per-wave a-exchange (5120 B)

    const int tid  = threadIdx.x;
    const int lane = tid & 63;
    const int wv   = tid >> 6;
    const int col  = lane & 15;            // A-row (=o) / B-col (=position)
    const int kg   = lane >> 4;            // k-group: k = kg*8 + i
    const int blk  = blockIdx.x;
    const int b    = blk >> 12;            // 4096 blocks per batch
    const int p0   = (blk & 4095) << 4;

    // ---- weight A-fragments (built once; K=32 logical) ----
    short8v A1f, A2f, A1w, A2w, Af2, Aw2;
    {
        const int c0 = (kg & 1) * 8;       // kg0/2 -> cols 0-7, kg1/3 -> 8-15
#pragma unroll
        for (int i = 0; i < 8; ++i) {
            const float w1 = wf1[col*16 + c0 + i];
            unsigned u1 = __float_as_uint(w1);
            float lo1 = w1 - __uint_as_float(u1 & 0xFFFF0000u);
            A1f[i] = (short)(u1 >> 16);
            A2f[i] = (short)(__float_as_uint(lo1) >> 16);
            const float w2 = ww1[col*16 + c0 + i];
            unsigned u2 = __float_as_uint(w2);
            float lo2 = w2 - __uint_as_float(u2 & 0xFFFF0000u);
            A1w[i] = (short)(u2 >> 16);
            A2w[i] = (short)(__float_as_uint(lo2) >> 16);
            const float v2f = wf2[col*16 + c0 + i];
            const float v2w = ww2[col*16 + c0 + i];
            Af2[i] = (kg < 2)  ? (short)rhu16(v2f) : (short)0;   // [Wf2 | 0]
            Aw2[i] = (kg >= 2) ? (short)rhu16(v2w) : (short)0;   // [0 | Ww2]
        }
    }
    float b1f[4], b1w[4], b2f[4], b2w[4];
#pragma unroll
    for (int r = 0; r < 4; ++r) {          // D row o = kg*4 + r
        b1f[r] = bf1[kg*4+r]; b1w[r] = bw1[kg*4+r];
        b2f[r] = bf2[kg*4+r]; b2w[r] = bw2[kg*4+r];
    }

    const f32x4 zf4 = {0.f, 0.f, 0.f, 0.f};

    auto process = [&](int u, const float* xv) {
        // B-frag: k<16 -> Xhi (trunc), k>=16 -> Xlo (residual)
        short8v bx;
#pragma unroll
        for (int i = 0; i < 8; ++i) {
            const unsigned uu = __float_as_uint(xv[i]);
            const float lof = xv[i] - __uint_as_float(uu & 0xFFFF0000u);
            const unsigned lob = __float_as_uint(lof) >> 16;
            const unsigned hib = uu >> 16;
            bx[i] = (short)(kg >= 2 ? lob : hib);
        }
        f32x4 accf = zf4, accw = zf4;
        accf = __builtin_amdgcn_mfma_f32_16x16x32_bf16(A1f, bx, accf, 0, 0, 0);
        accf = __builtin_amdgcn_mfma_f32_16x16x32_bf16(A2f, bx, accf, 0, 0, 0);
        accw = __builtin_amdgcn_mfma_f32_16x16x32_bf16(A1w, bx, accw, 0, 0, 0);
        accw = __builtin_amdgcn_mfma_f32_16x16x32_bf16(A2w, bx, accw, 0, 0, 0);

        // activations -> packed bf16 -> per-wave LDS row (af @0, aw @48)
        const float a0 = ftanh(accf[0]+b1f[0]), a1 = ftanh(accf[1]+b1f[1]);
        const float a2 = ftanh(accf[2]+b1f[2]), a3 = ftanh(accf[3]+b1f[3]);
        const float w0 = ftanh(accw[0]+b1w[0]), w1 = ftanh(accw[1]+b1w[1]);
        const float w2 = ftanh(accw[2]+b1w[2]), w3 = ftanh(accw[3]+b1w[3]);
        char* base = sAfaw[wv] + col * 80;
        *(uint2*)(base + kg*8)      = make_uint2((rhu16(a1)<<16)|rhu16(a0), (rhu16(a3)<<16)|rhu16(a2));
        *(uint2*)(base + 48 + kg*8) = make_uint2((rhu16(w1)<<16)|rhu16(w0), (rhu16(w3)<<16)|rhu16(w2));
        // B2 = [af ; aw]: kg0 af0-7, kg1 af8-15, kg2 aw0-7, kg3 aw8-15
        const short8v b2 = *(const short8v*)(base + ((kg & 1) * 16 + (kg >> 1) * 48));
        f32x4 acz = __builtin_amdgcn_mfma_f32_16x16x32_bf16(Af2, b2, zf4, 0, 0, 0);
        f32x4 acw = __builtin_amdgcn_mfma_f32_16x16x32_bf16(Aw2, b2, zf4, 0, 0, 0);

        // pack (z snorm16 | f unorm16) -> one b128 write, layout [u][p][c]
        uint4 pk;
        {
            unsigned w_[4];
#pragma unroll
            for (int r = 0; r < 4; ++r) {
                const float z = ftanh(acz[r] + b2f[r]);
                const float f = fsigm(acw[r] + b2w[r]);
                const int   zi = (int)__builtin_rintf(z * 32767.0f);
                const unsigned fu = (unsigned)(f * 65535.0f + 0.5f);
                w_[r] = ((unsigned)zi << 16) | (fu & 0xFFFFu);
            }
            pk = make_uint4(w_[0], w_[1], w_[2], w_[3]);
        }
        *(uint4*)&sGate[u][col][kg*4] = pk;
    };

    // ---- phase 1: 3-buffer register prefetch, 2 units ahead ----
    const unsigned xbase = (unsigned)b * BS + (unsigned)p0 + (unsigned)col
                         + (unsigned)((kg & 1) * 8) * CS;
#define LOADU(dst, u_) { const float* xp = x + (size_t)xbase + (size_t)(u_) * TS; \
    _Pragma("unroll") for (int i = 0; i < 8; ++i) (dst)[i] = xp[i * CS]; }

    float xs0[8], xs1[8], xs2[8];
    LOADU(xs0, wv)                       // u = wv (always < 31)
    LOADU(xs1, wv + 4)                   // wv+4 <= 7 < 31
#pragma unroll
    for (int k = 0; k < 8; ++k) {
        const int u  = wv + 4 * k;
        const int uf = u + 8;            // load 2 ahead
        if ((k % 3) == 0) {
            if (uf < TDIM) LOADU(xs2, uf)
            if (u  < TDIM) process(u, xs0);
        } else if ((k % 3) == 1) {
            if (uf < TDIM) LOADU(xs0, uf)
            if (u  < TDIM) process(u, xs1);
        } else {
            if (uf < TDIM) LOADU(xs1, uf)
            if (u  < TDIM) process(u, xs2);
        }
    }
#undef LOADU
    __syncthreads();

    // ---- phase 2: scan (thread = (c, p)) ----
    {
        const int c = tid >> 4, p = tid & 15;
        const unsigned oidx = (unsigned)b * BS + (unsigned)c * CS + (unsigned)p0 + (unsigned)p;
        float h = 0.f, s = 0.f;
#pragma unroll 1
        for (int t = 0; t < TDIM; ++t) {
            const int w = (int)sGate[t][p][c];
            const float z = (float)(w >> 16) * (1.0f / 32767.0f);
            const float f = (float)(w & 0xFFFF) * (1.0f / 65535.0f);
            h = fmaf(f, h - z, z);          // f*h + (1-f)*z
            s += h;
            if (BF16H) hb[oidx + (unsigned)t * TS] = (unsigned short)rhu16(h);
            else       out[oidx + (unsigned)t * TS] = h;
        }
#pragma unroll
        for (int off = 8; off; off >>= 1) s += __shfl_down(s, off, 16);
        if (p == 0) partials[blk * 16 + c] = s;
    }
}

__global__ __launch_bounds__(1024) void k2_attention(
    const float* __restrict__ partials, const float* __restrict__ wsca,
    const float* __restrict__ bsca, float* __restrict__ att)
{
    __shared__ float red[2][16][32];
    __shared__ float gap[2][16];
    const int tid = threadIdx.x;
    {
        const int b = tid >> 9, c = (tid >> 5) & 15, seg = tid & 31;
        float s = 0.f;
        const float* p = partials + (size_t)(b * 4096 + seg * 128) * 16 + c;
        for (int j = 0; j < 128; ++j) s += p[j * 16];
        red[b][c][seg] = s;
    }
    __syncthreads();
    if (tid < 32) {
        const int b = tid >> 4, c = tid & 15;
        float s = 0.f;
#pragma unroll
        for (int g = 0; g < 32; ++g) s += red[b][c][g];
        gap[b][c] = s * GAP_INV;
    }
    __syncthreads();
    if (tid < 32) {
        const int b = tid >> 4, o = tid & 15;
        float acc = bsca[o];
#pragma unroll
        for (int c = 0; c < 16; ++c) acc = fmaf(wsca[o*16 + c], gap[b][c], acc);
        att[b*16 + o] = fsigm(acc);
    }
}

// bf16-h path: read h (bf16, ws), write fp32 out. grid (248, 32) x 1024: exact.
__global__ __launch_bounds__(1024) void k3_scale_b(
    const unsigned short* __restrict__ hb, const float* __restrict__ att,
    float* __restrict__ out)
{
    const int bc = blockIdx.y;
    const float a = att[bc];
    const unsigned i = blockIdx.x * 1024 + threadIdx.x;     // < 253,952 = CS/8
    const size_t base = (size_t)bc * CS;
    const ushort8v v = ((const ushort8v*)(hb + base))[i];
    float4 o1, o2;
    o1.x = bf2f(v[0])*a; o1.y = bf2f(v[1])*a; o1.z = bf2f(v[2])*a; o1.w = bf2f(v[3])*a;
    o2.x = bf2f(v[4])*a; o2.y = bf2f(v[5])*a; o2.z = bf2f(v[6])*a; o2.w = bf2f(v[7])*a;
    float4* op = (float4*)(out + base);
    op[i*2]     = o1;
    op[i*2 + 1] = o2;
}

// fallback: in-place fp32 scale
__global__ __launch_bounds__(1024) void k3_scale_a(
    const float* __restrict__ att, float* __restrict__ out)
{
    const int bc = blockIdx.y;
    const float a = att[bc];
    const unsigned i = blockIdx.x * 1024 + threadIdx.x;
    float4* op = (float4*)(out + (size_t)bc * CS);
    float4 v1 = op[i*2], v2 = op[i*2 + 1];
    v1.x *= a; v1.y *= a; v1.z *= a; v1.w *= a;
    v2.x *= a; v2.y *= a; v2.z *= a; v2.w *= a;
    op[i*2] = v1; op[i*2 + 1] = v2;
}

extern "C" void kernel_launch(void* const* d_in, const int* in_sizes, int n_in,
                              void* d_out, int out_size, void* d_ws, size_t ws_size,
                              hipStream_t stream) {
    const float* x    = (const float*)d_in[0];
    const float* wf1  = (const float*)d_in[1];
    const float* bf1  = (const float*)d_in[2];
    const float* wf2  = (const float*)d_in[3];
    const float* bf2  = (const float*)d_in[4];
    const float* ww1  = (const float*)d_in[5];
    const float* bw1  = (const float*)d_in[6];
    const float* ww2  = (const float*)d_in[7];
    const float* bw2  = (const float*)d_in[8];
    const float* wsca = (const float*)d_in[9];
    const float* bsca = (const float*)d_in[10];
    float* out = (float*)d_out;

    const size_t hbBytes   = (size_t)NTOT * 2;               // 130,023,424
    const size_t partBytes = (size_t)K1_BLOCKS * 16 * 4;     // 524,288
    const bool bf16h = ws_size >= hbBytes + partBytes + 256;

    unsigned short* hb = (unsigned short*)d_ws;
    float* partials = bf16h ? (float*)((char*)d_ws + hbBytes) : (float*)d_ws;
    float* att = partials + K1_BLOCKS * 16;

    if (bf16h) {
        k1_fused<true><<<K1_BLOCKS, 256, 0, stream>>>(x, wf1, bf1, wf2, bf2,
            ww1, bw1, ww2, bw2, out, hb, partials);
        k2_attention<<<1, 1024, 0, stream>>>(partials, wsca, bsca, att);
        k3_scale_b<<<dim3(248, 32), 1024, 0, stream>>>(hb, att, out);
    } else {
        k1_fused<false><<<K1_BLOCKS, 256, 0, stream>>>(x, wf1, bf1, wf2, bf2,
            ww1, bw1, ww2, bw2, out, hb, partials);
        k2_attention<<<1, 1024, 0, stream>>>(partials, wsca, bsca, att);
        k3_scale_a<<<dim3(248, 32), 1024, 0, stream>>>(att, out);
    }
}

// Round 6
// 352.388 us; speedup vs baseline: 2.9966x; 1.0147x over previous
//
#include <hip/hip_runtime.h>
#include <hip/hip_bf16.h>

// x [B=2, C=16, T=31, H=256, W=256] fp32
#define TDIM 31
#define TS   65536                 // t stride (H*W)
#define CS   (TDIM * TS)           // c stride = 2,031,616
#define BS   (16 * CS)             // b stride
#define NTOT (2 * BS)              // 65,011,712
#define K1_BLOCKS 8192             // 16 positions per block
#define GAP_INV (1.0f / (31.0f * 65536.0f))

typedef __attribute__((ext_vector_type(8))) short short8v;     // 8 bf16 (4 VGPR)
typedef __attribute__((ext_vector_type(4))) float f32x4;       // MFMA C/D
typedef __attribute__((ext_vector_type(8))) unsigned short ushort8v;

__device__ __forceinline__ float frcp(float v){ return __builtin_amdgcn_rcpf(v); }
__device__ __forceinline__ float fexp2_(float v){ return __builtin_amdgcn_exp2f(v); }
__device__ __forceinline__ float ftanh(float x){ float e = fexp2_(x*2.8853900817779268f); return 1.0f - 2.0f*frcp(e+1.0f); }
__device__ __forceinline__ float fsigm(float x){ float e = fexp2_(x*-1.4426950408889634f); return frcp(1.0f+e); }
__device__ __forceinline__ unsigned rhu16(float x){ return (__float_as_uint(x) + 0x8000u) >> 16; }
__device__ __forceinline__ float bf2f(unsigned b){ return __uint_as_float(b << 16); }
// pack [hi16(x1) : hi16(x0)] in one v_perm
__device__ __forceinline__ unsigned pkhi(unsigned u0, unsigned u1){ return __builtin_amdgcn_perm(u1, u0, 0x07060302u); }

// Block: 16 positions x all 31 timesteps, 256 threads = 4 waves.
// Phase 1: wave w handles units u = w, w+4, ... (unit = one t of 16 positions).
//   4-buffer register prefetch (3 units = ~1000cy ahead). Per unit: B=[Xhi;Xlo]
//   K-split MFMAs for conv1 (both branches, bias as C-init), tanh, LDS
//   a-exchange, conv2 = 2 MFMAs, (z,f) packed snorm16/unorm16 -> ds_write_b128.
// Phase 2: single wave, lane=(cg,p) scans 4 channels via conflict-free
//   ds_read_b128, stores h (bf16 to ws or f32 to out), GAP partials.
template<bool BF16H>
__global__ __launch_bounds__(256, 4) void k1_fused(
    const float* __restrict__ x,
    const float* __restrict__ wf1, const float* __restrict__ bf1,
    const float* __restrict__ wf2, const float* __restrict__ bf2,
    const float* __restrict__ ww1, const float* __restrict__ bw1,
    const float* __restrict__ ww2, const float* __restrict__ bw2,
    float* __restrict__ out, unsigned short* __restrict__ hb,
    float* __restrict__ partials)
{
    __shared__ unsigned int sGate[TDIM][16][16];     // (z snorm16)<<16 | f unorm16; 31744 B
    __shared__ alignas(16) char sAfaw[4][1024];      // per-wave a-exchange, 64 B/col

    const int tid  = threadIdx.x;
    const int lane = tid & 63;
    const int wv   = tid >> 6;
    const int col  = lane & 15;            // A-row (=o) / B-col (=position)
    const int kg   = lane >> 4;            // k-group: k = kg*8 + i
    const bool lok = (kg >= 2);            // this lane's B-elems are lo-residuals
    const int blk  = blockIdx.x;
    const int b    = blk >> 12;            // 4096 blocks per batch
    const int p0   = (blk & 4095) << 4;

    // ---- weight A-fragments (built once; K=32 logical) ----
    short8v A1f, A2f, A1w, A2w, Af2, Aw2;
    {
        const int c0 = (kg & 1) * 8;       // kg0/2 -> cols 0-7, kg1/3 -> 8-15
#pragma unroll
        for (int i = 0; i < 8; ++i) {
            const float w1 = wf1[col*16 + c0 + i];
            unsigned u1 = __float_as_uint(w1);
            float lo1 = w1 - __uint_as_float(u1 & 0xFFFF0000u);
            A1f[i] = (short)(u1 >> 16);
            A2f[i] = (short)(__float_as_uint(lo1) >> 16);
            const float w2 = ww1[col*16 + c0 + i];
            unsigned u2 = __float_as_uint(w2);
            float lo2 = w2 - __uint_as_float(u2 & 0xFFFF0000u);
            A1w[i] = (short)(u2 >> 16);
            A2w[i] = (short)(__float_as_uint(lo2) >> 16);
            const float v2f = wf2[col*16 + c0 + i];
            const float v2w = ww2[col*16 + c0 + i];
            Af2[i] = (kg < 2)  ? (short)rhu16(v2f) : (short)0;   // [Wf2 | 0]
            Aw2[i] = (kg >= 2) ? (short)rhu16(v2w) : (short)0;   // [0 | Ww2]
        }
    }
    f32x4 b1fv, b1wv, b2fv, b2wv;          // bias vectors: D row o = kg*4 + r
#pragma unroll
    for (int r = 0; r < 4; ++r) {
        b1fv[r] = bf1[kg*4+r]; b1wv[r] = bw1[kg*4+r];
        b2fv[r] = bf2[kg*4+r]; b2wv[r] = bw2[kg*4+r];
    }

    auto process = [&](int u, const float* xv) {
        // B-frag: k<16 -> Xhi (trunc), k>=16 -> Xlo (residual); v_perm packing
        unsigned H[4], L[4];
#pragma unroll
        for (int j = 0; j < 4; ++j) {
            const unsigned u0 = __float_as_uint(xv[2*j]);
            const unsigned u1 = __float_as_uint(xv[2*j+1]);
            const float l0 = xv[2*j]   - __uint_as_float(u0 & 0xFFFF0000u);
            const float l1 = xv[2*j+1] - __uint_as_float(u1 & 0xFFFF0000u);
            H[j] = pkhi(u0, u1);
            L[j] = pkhi(__float_as_uint(l0), __float_as_uint(l1));
        }
        uint4 bxu;
        bxu.x = lok ? L[0] : H[0]; bxu.y = lok ? L[1] : H[1];
        bxu.z = lok ? L[2] : H[2]; bxu.w = lok ? L[3] : H[3];
        const short8v bx = __builtin_bit_cast(short8v, bxu);

        f32x4 accf = b1fv, accw = b1wv;    // bias as C-init
        accf = __builtin_amdgcn_mfma_f32_16x16x32_bf16(A1f, bx, accf, 0, 0, 0);
        accf = __builtin_amdgcn_mfma_f32_16x16x32_bf16(A2f, bx, accf, 0, 0, 0);
        accw = __builtin_amdgcn_mfma_f32_16x16x32_bf16(A1w, bx, accw, 0, 0, 0);
        accw = __builtin_amdgcn_mfma_f32_16x16x32_bf16(A2w, bx, accw, 0, 0, 0);

        // activations -> packed bf16 -> per-wave LDS row (af @0, aw @32)
        const float a0 = ftanh(accf[0]), a1 = ftanh(accf[1]);
        const float a2 = ftanh(accf[2]), a3 = ftanh(accf[3]);
        const float w0 = ftanh(accw[0]), w1 = ftanh(accw[1]);
        const float w2 = ftanh(accw[2]), w3 = ftanh(accw[3]);
        char* base = sAfaw[wv] + col * 64;
        *(uint2*)(base + kg*8)      = make_uint2((rhu16(a1)<<16)|rhu16(a0), (rhu16(a3)<<16)|rhu16(a2));
        *(uint2*)(base + 32 + kg*8) = make_uint2((rhu16(w1)<<16)|rhu16(w0), (rhu16(w3)<<16)|rhu16(w2));
        // B2 = [af ; aw]: kg0 af0-7 @0, kg1 af8-15 @16, kg2 aw0-7 @32, kg3 aw8-15 @48
        const short8v b2 = *(const short8v*)(base + ((kg & 1) * 16 + (kg >> 1) * 32));
        f32x4 acz = b2fv, acw = b2wv;
        acz = __builtin_amdgcn_mfma_f32_16x16x32_bf16(Af2, b2, acz, 0, 0, 0);
        acw = __builtin_amdgcn_mfma_f32_16x16x32_bf16(Aw2, b2, acw, 0, 0, 0);

        // pack (z snorm16 | f unorm16) -> one b128 write, layout [u][p][c]
        unsigned w_[4];
#pragma unroll
        for (int r = 0; r < 4; ++r) {
            const float z = ftanh(acz[r]);
            const float f = fsigm(acw[r]);
            const int   zi = (int)__builtin_rintf(z * 32767.0f);
            const unsigned fu = (unsigned)(f * 65535.0f + 0.5f);
            w_[r] = ((unsigned)zi << 16) | (fu & 0xFFFFu);
        }
        *(uint4*)&sGate[u][col][kg*4] = make_uint4(w_[0], w_[1], w_[2], w_[3]);
    };

    // ---- phase 1: 4-buffer register prefetch, 3 units (~1000 cy) ahead ----
    const unsigned xbase = (unsigned)b * BS + (unsigned)p0 + (unsigned)col
                         + (unsigned)((kg & 1) * 8) * CS;
#define LOADU(dst, u_) { const float* xp = x + (size_t)xbase + (size_t)(u_) * TS; \
    _Pragma("unroll") for (int i = 0; i < 8; ++i) (dst)[i] = xp[i * CS]; }

    float xs0[8], xs1[8], xs2[8], xs3[8];
    LOADU(xs0, wv)                       // wv      < 31
    LOADU(xs1, wv + 4)                   // wv+4  <= 7  < 31
    LOADU(xs2, wv + 8)                   // wv+8  <= 11 < 31
#pragma unroll
    for (int k = 0; k < 8; ++k) {
        const int u  = wv + 4 * k;
        const int uf = u + 12;           // load 3 ahead
        switch (k & 3) {
            case 0: if (uf < TDIM) LOADU(xs3, uf) if (u < TDIM) process(u, xs0); break;
            case 1: if (uf < TDIM) LOADU(xs0, uf) if (u < TDIM) process(u, xs1); break;
            case 2: if (uf < TDIM) LOADU(xs1, uf) if (u < TDIM) process(u, xs2); break;
            default:if (uf < TDIM) LOADU(xs2, uf) if (u < TDIM) process(u, xs3); break;
        }
    }
#undef LOADU
    __syncthreads();

    // ---- phase 2: single-wave scan, lane = (cg, p), 4 channels per lane ----
    if (tid < 64) {
        const int cg = tid >> 4, p = tid & 15;
        const unsigned obase = (unsigned)b * BS + (unsigned)p0 + (unsigned)p;
        float h[4] = {0.f,0.f,0.f,0.f}, s[4] = {0.f,0.f,0.f,0.f};
#pragma unroll 1
        for (int t = 0; t < TDIM; ++t) {
            const uint4 w4 = *(const uint4*)&sGate[t][p][cg*4];   // conflict-free b128
#pragma unroll
            for (int j = 0; j < 4; ++j) {
                const int w = (int)(j==0 ? w4.x : j==1 ? w4.y : j==2 ? w4.z : w4.w);
                const float z = (float)(w >> 16) * (1.0f / 32767.0f);
                const float f = (float)(w & 0xFFFF) * (1.0f / 65535.0f);
                h[j] = fmaf(f, h[j] - z, z);          // f*h + (1-f)*z
                s[j] += h[j];
                const unsigned oidx = obase + (unsigned)(cg*4+j) * CS + (unsigned)t * TS;
                if (BF16H) hb[oidx] = (unsigned short)rhu16(h[j]);
                else       out[oidx] = h[j];
            }
        }
#pragma unroll
        for (int j = 0; j < 4; ++j) {
#pragma unroll
            for (int off = 8; off; off >>= 1) s[j] += __shfl_down(s[j], off, 16);
        }
        if (p == 0) {
#pragma unroll
            for (int j = 0; j < 4; ++j) partials[blk * 16 + cg*4 + j] = s[j];
        }
    }
}

__global__ __launch_bounds__(1024) void k2_attention(
    const float* __restrict__ partials, const float* __restrict__ wsca,
    const float* __restrict__ bsca, float* __restrict__ att)
{
    __shared__ float red[2][16][32];
    __shared__ float gap[2][16];
    const int tid = threadIdx.x;
    {
        const int b = tid >> 9, c = (tid >> 5) & 15, seg = tid & 31;
        float s = 0.f;
        const float* p = partials + (size_t)(b * 4096 + seg * 128) * 16 + c;
        for (int j = 0; j < 128; ++j) s += p[j * 16];
        red[b][c][seg] = s;
    }
    __syncthreads();
    if (tid < 32) {
        const int b = tid >> 4, c = tid & 15;
        float s = 0.f;
#pragma unroll
        for (int g = 0; g < 32; ++g) s += red[b][c][g];
        gap[b][c] = s * GAP_INV;
    }
    __syncthreads();
    if (tid < 32) {
        const int b = tid >> 4, o = tid & 15;
        float acc = bsca[o];
#pragma unroll
        for (int c = 0; c < 16; ++c) acc = fmaf(wsca[o*16 + c], gap[b][c], acc);
        att[b*16 + o] = fsigm(acc);
    }
}

// bf16-h path: read h (bf16, ws), write fp32 out. grid (248, 32) x 1024: exact.
__global__ __launch_bounds__(1024) void k3_scale_b(
    const unsigned short* __restrict__ hb, const float* __restrict__ att,
    float* __restrict__ out)
{
    const int bc = blockIdx.y;
    const float a = att[bc];
    const unsigned i = blockIdx.x * 1024 + threadIdx.x;     // < 253,952 = CS/8
    const size_t base = (size_t)bc * CS;
    const ushort8v v = ((const ushort8v*)(hb + base))[i];
    float4 o1, o2;
    o1.x = bf2f(v[0])*a; o1.y = bf2f(v[1])*a; o1.z = bf2f(v[2])*a; o1.w = bf2f(v[3])*a;
    o2.x = bf2f(v[4])*a; o2.y = bf2f(v[5])*a; o2.z = bf2f(v[6])*a; o2.w = bf2f(v[7])*a;
    float4* op = (float4*)(out + base);
    op[i*2]     = o1;
    op[i*2 + 1] = o2;
}

// fallback: in-place fp32 scale
__global__ __launch_bounds__(1024) void k3_scale_a(
    const float* __restrict__ att, float* __restrict__ out)
{
    const int bc = blockIdx.y;
    const float a = att[bc];
    const unsigned i = blockIdx.x * 1024 + threadIdx.x;
    float4* op = (float4*)(out + (size_t)bc * CS);
    float4 v1 = op[i*2], v2 = op[i*2 + 1];
    v1.x *= a; v1.y *= a; v1.z *= a; v1.w *= a;
    v2.x *= a; v2.y *= a; v2.z *= a; v2.w *= a;
    op[i*2] = v1; op[i*2 + 1] = v2;
}

extern "C" void kernel_launch(void* const* d_in, const int* in_sizes, int n_in,
                              void* d_out, int out_size, void* d_ws, size_t ws_size,
                              hipStream_t stream) {
    const float* x    = (const float*)d_in[0];
    const float* wf1  = (const float*)d_in[1];
    const float* bf1  = (const float*)d_in[2];
    const float* wf2  = (const float*)d_in[3];
    const float* bf2  = (const float*)d_in[4];
    const float* ww1  = (const float*)d_in[5];
    const float* bw1  = (const float*)d_in[6];
    const float* ww2  = (const float*)d_in[7];
    const float* bw2  = (const float*)d_in[8];
    const float* wsca = (const float*)d_in[9];
    const float* bsca = (const float*)d_in[10];
    float* out = (float*)d_out;

    const size_t hbBytes   = (size_t)NTOT * 2;               // 130,023,424
    const size_t partBytes = (size_t)K1_BLOCKS * 16 * 4;     // 524,288
    const bool bf16h = ws_size >= hbBytes + partBytes + 256;

    unsigned short* hb = (unsigned short*)d_ws;
    float* partials = bf16h ? (float*)((char*)d_ws + hbBytes) : (float*)d_ws;
    float* att = partials + K1_BLOCKS * 16;

    if (bf16h) {
        k1_fused<true><<<K1_BLOCKS, 256, 0, stream>>>(x, wf1, bf1, wf2, bf2,
            ww1, bw1, ww2, bw2, out, hb, partials);
        k2_attention<<<1, 1024, 0, stream>>>(partials, wsca, bsca, att);
        k3_scale_b<<<dim3(248, 32), 1024, 0, stream>>>(hb, att, out);
    } else {
        k1_fused<false><<<K1_BLOCKS, 256, 0, stream>>>(x, wf1, bf1, wf2, bf2,
            ww1, bw1, ww2, bw2, out, hb, partials);
        k2_attention<<<1, 1024, 0, stream>>>(partials, wsca, bsca, att);
        k3_scale_a<<<dim3(248, 32), 1024, 0, stream>>>(att, out);
    }
}